// Round 1
// baseline (343.751 us; speedup 1.0000x reference)
//
#include <hip/hip_runtime.h>

#define LN_EPS 1e-5f

// ---------------- CSR build ----------------

__global__ void k_count(const int* __restrict__ dst, int E, int* __restrict__ cnt) {
  int e = blockIdx.x * blockDim.x + threadIdx.x;
  if (e < E) atomicAdd(&cnt[dst[e]], 1);
}

__global__ __launch_bounds__(1024) void k_scan(const int* __restrict__ cnt, int n,
                                               int* __restrict__ off, int* __restrict__ cur) {
  __shared__ int part[1024];
  const int tid = threadIdx.x;
  const int per = (n + 1023) >> 10;
  const int base = tid * per;
  int s = 0;
  for (int i = 0; i < per; ++i) {
    int idx = base + i;
    if (idx < n) s += cnt[idx];
  }
  part[tid] = s;
  __syncthreads();
  for (int d = 1; d < 1024; d <<= 1) {
    int v = (tid >= d) ? part[tid - d] : 0;
    __syncthreads();
    part[tid] += v;
    __syncthreads();
  }
  int run = (tid == 0) ? 0 : part[tid - 1];
  for (int i = 0; i < per; ++i) {
    int idx = base + i;
    if (idx < n) {
      off[idx] = run;
      cur[idx] = run;
      run += cnt[idx];
    }
  }
  if (tid == 1023) off[n] = part[1023];
}

__global__ void k_fill(const int* __restrict__ src, const int* __restrict__ dst, int E,
                       int* __restrict__ cur, int* __restrict__ srclist) {
  int e = blockIdx.x * blockDim.x + threadIdx.x;
  if (e < E) {
    int p = atomicAdd(&cur[dst[e]], 1);
    srclist[p] = src[e];
  }
}

// ---------------- mean aggregation: one wave per dst node ----------------
// out[d] = mean(X[srclist[off[d]..off[d+1]]]); optional (v-mu)*inv affine

template <int VEC>
__global__ __launch_bounds__(64) void k_gather(
    const float* __restrict__ X, int F,
    const int* __restrict__ off, const int* __restrict__ srclist,
    float* __restrict__ out, const float* __restrict__ stats) {
  const int d = blockIdx.x;
  const int lane = threadIdx.x;
  const int b = off[d], e = off[d + 1];
  float acc[VEC];
#pragma unroll
  for (int i = 0; i < VEC; ++i) acc[i] = 0.f;
  const float* Xl = X + (size_t)lane * VEC;
  for (int j = b; j < e; ++j) {
    int s = srclist[j];
    const float* row = Xl + (size_t)s * F;
    if constexpr (VEC == 2) {
      float2 v = *(const float2*)row;
      acc[0] += v.x; acc[1] += v.y;
    } else {
      float4 v = *(const float4*)row;
      acc[0] += v.x; acc[1] += v.y; acc[2] += v.z; acc[3] += v.w;
    }
  }
  float scale = 1.f / fmaxf((float)(e - b), 1.f);
  float mu = 0.f, inv = 1.f;
  if (stats) { mu = stats[2]; inv = stats[3]; }
#pragma unroll
  for (int i = 0; i < VEC; ++i) acc[i] = (acc[i] * scale - mu) * inv;
  float* orow = out + (size_t)d * F + lane * VEC;
  if constexpr (VEC == 2) {
    *(float2*)orow = make_float2(acc[0], acc[1]);
  } else {
    *(float4*)orow = make_float4(acc[0], acc[1], acc[2], acc[3]);
  }
}

// ---------------- dual-source tiled fp32 GEMM ----------------
// C[M][N] = act( A0[M][K] @ B0[N][K]^T + A1[M][K] @ B1[N][K]^T + bias )
// AFF0: apply (v-mu)*inv to A0 elements. STATS: accumulate sum/sumsq of C.

template <int BM, int BN, int TM, int TN, bool RELU, bool STATS, bool AFF0>
__global__ __launch_bounds__(256) void k_gemm2src(
    const float* __restrict__ A0, const float* __restrict__ A1,
    const float* __restrict__ B0, const float* __restrict__ B1,
    const float* __restrict__ bias, float* __restrict__ C,
    int M, int N, int K, const float* __restrict__ stats,
    float* __restrict__ statAcc) {
  constexpr int BK = 16;
  __shared__ __align__(16) float As[BK][BM + 4];
  __shared__ __align__(16) float Bs[BK][BN + 4];

  const int tid = threadIdx.x;
  const int tx = tid & 15;        // N direction
  const int ty = tid >> 4;        // M direction
  const int mBase = blockIdx.y * BM;
  const int nBase = blockIdx.x * BN;

  float mu = 0.f, inv = 1.f;
  if constexpr (AFF0) { mu = stats[2]; inv = stats[3]; }

  float acc[TM][TN];
#pragma unroll
  for (int i = 0; i < TM; ++i)
#pragma unroll
    for (int j = 0; j < TN; ++j) acc[i][j] = 0.f;

  for (int s = 0; s < 2; ++s) {
    const float* __restrict__ A = s ? A1 : A0;
    const float* __restrict__ Bm = s ? B1 : B0;
    const bool doAff = AFF0 && (s == 0);
    for (int k0 = 0; k0 < K; k0 += BK) {
      // stage A tile (BM x BK)
      if (tid < BM * 4) {
        int m = tid >> 2, kq = (tid & 3) << 2;
        int mg = mBase + m;
        float4 v = make_float4(0.f, 0.f, 0.f, 0.f);
        if (mg < M) {
          v = *(const float4*)(A + (size_t)mg * K + k0 + kq);
          if (doAff) {
            v.x = (v.x - mu) * inv; v.y = (v.y - mu) * inv;
            v.z = (v.z - mu) * inv; v.w = (v.w - mu) * inv;
          }
        }
        As[kq + 0][m] = v.x; As[kq + 1][m] = v.y;
        As[kq + 2][m] = v.z; As[kq + 3][m] = v.w;
      }
      // stage B tile (BN x BK); N is a multiple of BN, K of BK
      {
        int n = tid >> 2, kq = (tid & 3) << 2;
        int ng = nBase + n;
        float4 v = *(const float4*)(Bm + (size_t)ng * K + k0 + kq);
        Bs[kq + 0][n] = v.x; Bs[kq + 1][n] = v.y;
        Bs[kq + 2][n] = v.z; Bs[kq + 3][n] = v.w;
      }
      __syncthreads();
#pragma unroll
      for (int kk = 0; kk < BK; ++kk) {
        float a[TM], b[TN];
#pragma unroll
        for (int i = 0; i < TM; ++i) a[i] = As[kk][ty * TM + i];
#pragma unroll
        for (int j = 0; j < TN; ++j) b[j] = Bs[kk][tx * TN + j];
#pragma unroll
        for (int i = 0; i < TM; ++i)
#pragma unroll
          for (int j = 0; j < TN; ++j) acc[i][j] = fmaf(a[i], b[j], acc[i][j]);
      }
      __syncthreads();
    }
  }

  // epilogue
  float bj[TN];
#pragma unroll
  for (int j = 0; j < TN; ++j) bj[j] = bias[nBase + tx * TN + j];

  float s1 = 0.f, s2 = 0.f;
#pragma unroll
  for (int i = 0; i < TM; ++i) {
    int mg = mBase + ty * TM + i;
    if (mg < M) {
      float4 v;
      float* vp = &v.x;
#pragma unroll
      for (int j = 0; j < TN; ++j) {
        float c = acc[i][j] + bj[j];
        if constexpr (RELU) c = fmaxf(c, 0.f);
        vp[j] = c;
        if constexpr (STATS) { s1 += c; s2 += c * c; }
      }
      *(float4*)(C + (size_t)mg * N + nBase + tx * TN) = v;
    }
  }

  if constexpr (STATS) {
#pragma unroll
    for (int o = 32; o > 0; o >>= 1) {
      s1 += __shfl_down(s1, o);
      s2 += __shfl_down(s2, o);
    }
    if ((tid & 63) == 0) {
      atomicAdd(&statAcc[0], s1);
      atomicAdd(&statAcc[1], s2);
    }
  }
}

__global__ void k_finalize(float* stats, float invN) {
  float mu = stats[0] * invN;
  float var = stats[1] * invN - mu * mu;
  stats[2] = mu;
  stats[3] = 1.f / sqrtf(var + LN_EPS);
}

// ---------------- launch ----------------

extern "C" void kernel_launch(void* const* d_in, const int* in_sizes, int n_in,
                              void* d_out, int out_size, void* d_ws, size_t ws_size,
                              hipStream_t stream) {
  const float* x   = (const float*)d_in[0];
  const float* Ws1 = (const float*)d_in[1];
  const float* Wn1 = (const float*)d_in[2];
  const float* b1  = (const float*)d_in[3];
  const float* Ws2 = (const float*)d_in[4];
  const float* Wn2 = (const float*)d_in[5];
  const float* b2  = (const float*)d_in[6];
  const int* src1  = (const int*)d_in[7];
  const int* dst1  = (const int*)d_in[8];
  const int* src2  = (const int*)d_in[9];
  const int* dst2  = (const int*)d_in[10];

  const int E1 = in_sizes[7];
  const int E2 = in_sizes[9];
  const int N1 = 20000, N2 = 4000;
  const int FIN = 128, FH = 256, FOUT = 64;

  char* w = (char*)d_ws;
  auto alloc = [&](size_t bytes) {
    char* p = w;
    w += (bytes + 255) & ~(size_t)255;
    return p;
  };
  int* cnt1 = (int*)alloc((size_t)N1 * 4);
  int* off1 = (int*)alloc((size_t)(N1 + 1) * 4);
  int* cur1 = (int*)alloc((size_t)N1 * 4);
  int* sl1  = (int*)alloc((size_t)E1 * 4);
  int* cnt2 = (int*)alloc((size_t)N2 * 4);
  int* off2 = (int*)alloc((size_t)(N2 + 1) * 4);
  int* cur2 = (int*)alloc((size_t)N2 * 4);
  int* sl2  = (int*)alloc((size_t)E2 * 4);
  float* agg1  = (float*)alloc((size_t)N1 * FIN * 4);
  float* h     = (float*)alloc((size_t)N1 * FH * 4);
  float* agg2  = (float*)alloc((size_t)N2 * FH * 4);
  float* stats = (float*)alloc(64);

  hipMemsetAsync(cnt1, 0, (size_t)N1 * 4, stream);
  hipMemsetAsync(cnt2, 0, (size_t)N2 * 4, stream);
  hipMemsetAsync(stats, 0, 16, stream);

  // ---- layer 1 ----
  k_count<<<(E1 + 255) / 256, 256, 0, stream>>>(dst1, E1, cnt1);
  k_scan<<<1, 1024, 0, stream>>>(cnt1, N1, off1, cur1);
  k_fill<<<(E1 + 255) / 256, 256, 0, stream>>>(src1, dst1, E1, cur1, sl1);
  k_gather<2><<<N1, 64, 0, stream>>>(x, FIN, off1, sl1, agg1, nullptr);

  dim3 g1(FH / 64, (N1 + 63) / 64);
  k_gemm2src<64, 64, 4, 4, true, true, false><<<g1, 256, 0, stream>>>(
      x, agg1, Ws1, Wn1, b1, h, N1, FH, FIN, stats, stats);
  k_finalize<<<1, 1, 0, stream>>>(stats, 1.f / ((float)N1 * (float)FH));

  // ---- layer 2 ----
  k_count<<<(E2 + 255) / 256, 256, 0, stream>>>(dst2, E2, cnt2);
  k_scan<<<1, 1024, 0, stream>>>(cnt2, N2, off2, cur2);
  k_fill<<<(E2 + 255) / 256, 256, 0, stream>>>(src2, dst2, E2, cur2, sl2);
  k_gather<4><<<N2, 64, 0, stream>>>(h, FH, off2, sl2, agg2, stats);

  dim3 g2(FOUT / 64, (N2 + 31) / 32);
  k_gemm2src<32, 64, 2, 4, false, false, true><<<g2, 256, 0, stream>>>(
      h, agg2, Ws2, Wn2, b2, (float*)d_out, N2, FOUT, FH, stats, nullptr);
}

// Round 2
// 341.748 us; speedup vs baseline: 1.0059x; 1.0059x over previous
//
#include <hip/hip_runtime.h>

#define LN_EPS 1e-5f

typedef __attribute__((ext_vector_type(8))) short short8v;
typedef __attribute__((ext_vector_type(4))) float f32x4;

__device__ __forceinline__ unsigned short f2bf(float f) {
  union { float f; unsigned u; } v; v.f = f;
  unsigned r = v.u + 0x7FFFu + ((v.u >> 16) & 1u);
  return (unsigned short)(r >> 16);
}
__device__ __forceinline__ float bf2f(unsigned short b) {
  union { unsigned u; float f; } v; v.u = ((unsigned)b) << 16;
  return v.f;
}

// ---------------- dtype conversion ----------------

__global__ void k_cvt(const float* __restrict__ in, unsigned short* __restrict__ out, int n4) {
  int i = blockIdx.x * blockDim.x + threadIdx.x;
  if (i < n4) {
    float4 v = ((const float4*)in)[i];
    ushort4 o;
    o.x = f2bf(v.x); o.y = f2bf(v.y); o.z = f2bf(v.z); o.w = f2bf(v.w);
    ((ushort4*)out)[i] = o;
  }
}

__global__ void k_cvt4(const float* a, unsigned short* oa, int na,
                       const float* b, unsigned short* ob, int nb,
                       const float* c, unsigned short* oc, int nc,
                       const float* d, unsigned short* od, int nd) {
  int i = blockIdx.x * blockDim.x + threadIdx.x;
  if (i < na) { oa[i] = f2bf(a[i]); return; }
  i -= na;
  if (i < nb) { ob[i] = f2bf(b[i]); return; }
  i -= nb;
  if (i < nc) { oc[i] = f2bf(c[i]); return; }
  i -= nc;
  if (i < nd) { od[i] = f2bf(d[i]); }
}

// apply (v-mu)*inv to bf16 rows -> bf16
__global__ void k_affine(const unsigned short* __restrict__ h, unsigned short* __restrict__ out,
                         int n4, const float* __restrict__ stats) {
  int i = blockIdx.x * blockDim.x + threadIdx.x;
  if (i < n4) {
    float mu = stats[2], inv = stats[3];
    ushort4 v = ((const ushort4*)h)[i];
    ushort4 o;
    o.x = f2bf((bf2f(v.x) - mu) * inv);
    o.y = f2bf((bf2f(v.y) - mu) * inv);
    o.z = f2bf((bf2f(v.z) - mu) * inv);
    o.w = f2bf((bf2f(v.w) - mu) * inv);
    ((ushort4*)out)[i] = o;
  }
}

// ---------------- CSR build ----------------

__global__ void k_count(const int* __restrict__ dst, int E, int* __restrict__ cnt) {
  int e = blockIdx.x * blockDim.x + threadIdx.x;
  if (e < E) atomicAdd(&cnt[dst[e]], 1);
}

__global__ __launch_bounds__(1024) void k_scan(const int* __restrict__ cnt, int n,
                                               int* __restrict__ off, int* __restrict__ cur) {
  __shared__ int part[1024];
  const int tid = threadIdx.x;
  const int per = (n + 1023) >> 10;
  const int base = tid * per;
  int s = 0;
  for (int i = 0; i < per; ++i) {
    int idx = base + i;
    if (idx < n) s += cnt[idx];
  }
  part[tid] = s;
  __syncthreads();
  for (int d = 1; d < 1024; d <<= 1) {
    int v = (tid >= d) ? part[tid - d] : 0;
    __syncthreads();
    part[tid] += v;
    __syncthreads();
  }
  int run = (tid == 0) ? 0 : part[tid - 1];
  for (int i = 0; i < per; ++i) {
    int idx = base + i;
    if (idx < n) {
      off[idx] = run;
      cur[idx] = run;
      run += cnt[idx];
    }
  }
  if (tid == 1023) off[n] = part[1023];
}

__global__ void k_fill(const int* __restrict__ src, const int* __restrict__ dst, int E,
                       int* __restrict__ cur, int* __restrict__ srclist) {
  int e = blockIdx.x * blockDim.x + threadIdx.x;
  if (e < E) {
    int p = atomicAdd(&cur[dst[e]], 1);
    srclist[p] = src[e];
  }
}

// ---------------- mean aggregation (bf16 in/out, fp32 accum) ----------------
// VECB = bf16 elems per lane (F/64)

template <int VECB>
__global__ __launch_bounds__(64) void k_gather_bf(
    const unsigned short* __restrict__ X, int F,
    const int* __restrict__ off, const int* __restrict__ sl,
    unsigned short* __restrict__ out, const float* __restrict__ stats) {
  const int d = blockIdx.x;
  const int lane = threadIdx.x;
  const int b = off[d], e = off[d + 1];
  float acc[VECB];
#pragma unroll
  for (int i = 0; i < VECB; ++i) acc[i] = 0.f;
  const unsigned short* Xl = X + lane * VECB;
  for (int j = b; j < e; ++j) {
    const unsigned short* row = Xl + (size_t)sl[j] * F;
    if constexpr (VECB == 2) {
      unsigned v = *(const unsigned*)row;
      acc[0] += bf2f((unsigned short)(v & 0xffff));
      acc[1] += bf2f((unsigned short)(v >> 16));
    } else {
      uint2 v = *(const uint2*)row;
      acc[0] += bf2f((unsigned short)(v.x & 0xffff));
      acc[1] += bf2f((unsigned short)(v.x >> 16));
      acc[2] += bf2f((unsigned short)(v.y & 0xffff));
      acc[3] += bf2f((unsigned short)(v.y >> 16));
    }
  }
  float scale = 1.f / fmaxf((float)(e - b), 1.f);
  float mu = 0.f, inv = 1.f;
  if (stats) { mu = stats[2]; inv = stats[3]; }
  unsigned short* orow = out + (size_t)d * F + lane * VECB;
  if constexpr (VECB == 2) {
    unsigned v = ((unsigned)f2bf((acc[1] * scale - mu) * inv) << 16) |
                 (unsigned)f2bf((acc[0] * scale - mu) * inv);
    *(unsigned*)orow = v;
  } else {
    uint2 v;
    v.x = ((unsigned)f2bf((acc[1] * scale - mu) * inv) << 16) |
          (unsigned)f2bf((acc[0] * scale - mu) * inv);
    v.y = ((unsigned)f2bf((acc[3] * scale - mu) * inv) << 16) |
          (unsigned)f2bf((acc[2] * scale - mu) * inv);
    *(uint2*)orow = v;
  }
}

// ---------------- dual-source bf16 MFMA GEMM ----------------
// C[M][N] = act( A0 @ B0^T + A1 @ B1^T + bias ), A:[M][K] bf16, B:[N][K] bf16
// block = 4 waves; wave w -> rows [by*64 + 16w, +16), cols [bx*64, +64) as 4 frags

template <bool RELU, bool STATS, bool OUT_BF16>
__global__ __launch_bounds__(256) void k_gemm_mfma(
    const unsigned short* __restrict__ A0, const unsigned short* __restrict__ A1,
    const unsigned short* __restrict__ B0, const unsigned short* __restrict__ B1,
    const float* __restrict__ bias, void* __restrict__ Cout,
    int M, int N, int K, float* __restrict__ statAcc) {
  const int lane = threadIdx.x & 63;
  const int wv = threadIdx.x >> 6;
  const int m0 = blockIdx.y * 64 + wv * 16;
  const int n0 = blockIdx.x * 64;
  const int r16 = lane & 15;
  const int hi = lane >> 4;
  int arow = m0 + r16;
  if (arow >= M) arow = M - 1;
  const int koff = hi * 8;

  f32x4 acc[4];
#pragma unroll
  for (int j = 0; j < 4; ++j) acc[j] = f32x4{0.f, 0.f, 0.f, 0.f};

#pragma unroll
  for (int s = 0; s < 2; ++s) {
    const unsigned short* A = s ? A1 : A0;
    const unsigned short* B = s ? B1 : B0;
    const unsigned short* ap = A + (size_t)arow * K + koff;
    const unsigned short* bp = B + (size_t)(n0 + r16) * K + koff;
    for (int k0 = 0; k0 < K; k0 += 32) {
      short8v a = *(const short8v*)(ap + k0);
#pragma unroll
      for (int j = 0; j < 4; ++j) {
        short8v b = *(const short8v*)(bp + (size_t)j * 16 * K + k0);
        acc[j] = __builtin_amdgcn_mfma_f32_16x16x32_bf16(a, b, acc[j], 0, 0, 0);
      }
    }
  }

  float s1 = 0.f, s2 = 0.f;
#pragma unroll
  for (int j = 0; j < 4; ++j) {
    const int col = n0 + j * 16 + r16;
    const float bj = bias[col];
#pragma unroll
    for (int r = 0; r < 4; ++r) {
      const int m = m0 + hi * 4 + r;
      float c = acc[j][r] + bj;
      if constexpr (RELU) c = fmaxf(c, 0.f);
      if (m < M) {
        if constexpr (STATS) { s1 += c; s2 += c * c; }
        if constexpr (OUT_BF16)
          ((unsigned short*)Cout)[(size_t)m * N + col] = f2bf(c);
        else
          ((float*)Cout)[(size_t)m * N + col] = c;
      }
    }
  }

  if constexpr (STATS) {
#pragma unroll
    for (int o = 32; o > 0; o >>= 1) {
      s1 += __shfl_down(s1, o);
      s2 += __shfl_down(s2, o);
    }
    if (lane == 0) {
      atomicAdd(&statAcc[0], s1);
      atomicAdd(&statAcc[1], s2);
    }
  }
}

__global__ void k_finalize(float* stats, float invN) {
  float mu = stats[0] * invN;
  float var = stats[1] * invN - mu * mu;
  stats[2] = mu;
  stats[3] = 1.f / sqrtf(var + LN_EPS);
}

// ---------------- launch ----------------

extern "C" void kernel_launch(void* const* d_in, const int* in_sizes, int n_in,
                              void* d_out, int out_size, void* d_ws, size_t ws_size,
                              hipStream_t stream) {
  const float* x   = (const float*)d_in[0];
  const float* Ws1 = (const float*)d_in[1];
  const float* Wn1 = (const float*)d_in[2];
  const float* b1  = (const float*)d_in[3];
  const float* Ws2 = (const float*)d_in[4];
  const float* Wn2 = (const float*)d_in[5];
  const float* b2  = (const float*)d_in[6];
  const int* src1  = (const int*)d_in[7];
  const int* dst1  = (const int*)d_in[8];
  const int* src2  = (const int*)d_in[9];
  const int* dst2  = (const int*)d_in[10];

  const int E1 = in_sizes[7];
  const int E2 = in_sizes[9];
  const int N0 = 100000, N1 = 20000, N2 = 4000;
  const int FIN = 128, FH = 256, FOUT = 64;

  char* w = (char*)d_ws;
  auto alloc = [&](size_t bytes) {
    char* p = w;
    w += (bytes + 255) & ~(size_t)255;
    return p;
  };
  int* cnt1 = (int*)alloc((size_t)N1 * 4);
  int* off1 = (int*)alloc((size_t)(N1 + 1) * 4);
  int* cur1 = (int*)alloc((size_t)N1 * 4);
  int* sl1  = (int*)alloc((size_t)E1 * 4);
  int* cnt2 = (int*)alloc((size_t)N2 * 4);
  int* off2 = (int*)alloc((size_t)(N2 + 1) * 4);
  int* cur2 = (int*)alloc((size_t)N2 * 4);
  int* sl2  = (int*)alloc((size_t)E2 * 4);
  unsigned short* xbf   = (unsigned short*)alloc((size_t)N0 * FIN * 2);
  unsigned short* agg1b = (unsigned short*)alloc((size_t)N1 * FIN * 2);
  unsigned short* hbf   = (unsigned short*)alloc((size_t)N1 * FH * 2);
  unsigned short* a02b  = (unsigned short*)alloc((size_t)N2 * FH * 2);
  unsigned short* agg2b = (unsigned short*)alloc((size_t)N2 * FH * 2);
  unsigned short* w1sb  = (unsigned short*)alloc((size_t)FH * FIN * 2);
  unsigned short* w1nb  = (unsigned short*)alloc((size_t)FH * FIN * 2);
  unsigned short* w2sb  = (unsigned short*)alloc((size_t)FOUT * FH * 2);
  unsigned short* w2nb  = (unsigned short*)alloc((size_t)FOUT * FH * 2);
  float* stats = (float*)alloc(64);

  hipMemsetAsync(cnt1, 0, (size_t)N1 * 4, stream);
  hipMemsetAsync(cnt2, 0, (size_t)N2 * 4, stream);
  hipMemsetAsync(stats, 0, 16, stream);

  // conversions
  {
    int n4 = N0 * FIN / 4;
    k_cvt<<<(n4 + 255) / 256, 256, 0, stream>>>(x, xbf, n4);
    int nw = FH * FIN * 2 + FOUT * FH * 2;
    k_cvt4<<<(nw + 255) / 256, 256, 0, stream>>>(Ws1, w1sb, FH * FIN, Wn1, w1nb, FH * FIN,
                                                 Ws2, w2sb, FOUT * FH, Wn2, w2nb, FOUT * FH);
  }

  // CSR builds
  k_count<<<(E1 + 255) / 256, 256, 0, stream>>>(dst1, E1, cnt1);
  k_scan<<<1, 1024, 0, stream>>>(cnt1, N1, off1, cur1);
  k_fill<<<(E1 + 255) / 256, 256, 0, stream>>>(src1, dst1, E1, cur1, sl1);
  k_count<<<(E2 + 255) / 256, 256, 0, stream>>>(dst2, E2, cnt2);
  k_scan<<<1, 1024, 0, stream>>>(cnt2, N2, off2, cur2);
  k_fill<<<(E2 + 255) / 256, 256, 0, stream>>>(src2, dst2, E2, cur2, sl2);

  // ---- layer 1 ----
  k_gather_bf<2><<<N1, 64, 0, stream>>>(xbf, FIN, off1, sl1, agg1b, nullptr);

  dim3 g1(FH / 64, (N1 + 63) / 64);
  k_gemm_mfma<true, true, true><<<g1, 256, 0, stream>>>(
      xbf, agg1b, w1sb, w1nb, b1, hbf, N1, FH, FIN, stats);
  k_finalize<<<1, 1, 0, stream>>>(stats, 1.f / ((float)N1 * (float)FH));

  // ---- layer 2 ----
  {
    int n4 = N2 * FH / 4;
    k_affine<<<(n4 + 255) / 256, 256, 0, stream>>>(hbf, a02b, n4, stats);
  }
  k_gather_bf<4><<<N2, 64, 0, stream>>>(hbf, FH, off2, sl2, agg2b, stats);

  dim3 g2(FOUT / 64, (N2 + 63) / 64);
  k_gemm_mfma<false, false, false><<<g2, 256, 0, stream>>>(
      a02b, agg2b, w2sb, w2nb, b2, (float*)d_out, N2, FOUT, FH, nullptr);
}

// Round 3
// 199.102 us; speedup vs baseline: 1.7265x; 1.7164x over previous
//
#include <hip/hip_runtime.h>

#define LN_EPS 1e-5f

typedef __attribute__((ext_vector_type(8))) short short8v;
typedef __attribute__((ext_vector_type(4))) float f32x4;

__device__ __forceinline__ unsigned short f2bf(float f) {
  union { float f; unsigned u; } v; v.f = f;
  unsigned r = v.u + 0x7FFFu + ((v.u >> 16) & 1u);
  return (unsigned short)(r >> 16);
}
__device__ __forceinline__ float bf2f(unsigned short b) {
  union { unsigned u; float f; } v; v.u = ((unsigned)b) << 16;
  return v.f;
}

// ---------------- fused dtype conversion: x (vec4) + all 4 weight matrices ----------------

__global__ __launch_bounds__(256) void k_cvt_all(
    const float* __restrict__ x, unsigned short* __restrict__ xbf, int n4x,
    const float* __restrict__ wa, unsigned short* __restrict__ oa, int na,
    const float* __restrict__ wb, unsigned short* __restrict__ ob, int nb,
    const float* __restrict__ wc, unsigned short* __restrict__ oc, int nc,
    const float* __restrict__ wd, unsigned short* __restrict__ od, int nd) {
  int i = blockIdx.x * 256 + threadIdx.x;
  if (i < n4x) {
    float4 v = ((const float4*)x)[i];
    ushort4 o;
    o.x = f2bf(v.x); o.y = f2bf(v.y); o.z = f2bf(v.z); o.w = f2bf(v.w);
    ((ushort4*)xbf)[i] = o;
    return;
  }
  i -= n4x;
  if (i < na) { oa[i] = f2bf(wa[i]); return; }
  i -= na;
  if (i < nb) { ob[i] = f2bf(wb[i]); return; }
  i -= nb;
  if (i < nc) { oc[i] = f2bf(wc[i]); return; }
  i -= nc;
  if (i < nd) { od[i] = f2bf(wd[i]); }
}

// apply (v-mu)*inv to bf16 rows -> bf16
__global__ void k_affine(const unsigned short* __restrict__ h, unsigned short* __restrict__ out,
                         int n4, const float* __restrict__ stats) {
  int i = blockIdx.x * blockDim.x + threadIdx.x;
  if (i < n4) {
    float mu = stats[2], inv = stats[3];
    ushort4 v = ((const ushort4*)h)[i];
    ushort4 o;
    o.x = f2bf((bf2f(v.x) - mu) * inv);
    o.y = f2bf((bf2f(v.y) - mu) * inv);
    o.z = f2bf((bf2f(v.z) - mu) * inv);
    o.w = f2bf((bf2f(v.w) - mu) * inv);
    ((ushort4*)out)[i] = o;
  }
}

// ---------------- CSR build (both graphs fused) ----------------

__global__ void k_count2(const int* __restrict__ d1, int E1, int* __restrict__ c1,
                         const int* __restrict__ d2, int E2, int* __restrict__ c2) {
  int e = blockIdx.x * blockDim.x + threadIdx.x;
  if (e < E1) atomicAdd(&c1[d1[e]], 1);
  else if (e < E1 + E2) atomicAdd(&c2[d2[e - E1]], 1);
}

__global__ __launch_bounds__(1024) void k_scan2(
    const int* __restrict__ c1, int n1, int* __restrict__ o1, int* __restrict__ u1,
    const int* __restrict__ c2, int n2, int* __restrict__ o2, int* __restrict__ u2) {
  const int* cnt = blockIdx.x ? c2 : c1;
  int n = blockIdx.x ? n2 : n1;
  int* off = blockIdx.x ? o2 : o1;
  int* cur = blockIdx.x ? u2 : u1;
  __shared__ int part[1024];
  const int tid = threadIdx.x;
  const int per = (n + 1023) >> 10;
  const int base = tid * per;
  int s = 0;
  for (int i = 0; i < per; ++i) {
    int idx = base + i;
    if (idx < n) s += cnt[idx];
  }
  part[tid] = s;
  __syncthreads();
  for (int d = 1; d < 1024; d <<= 1) {
    int v = (tid >= d) ? part[tid - d] : 0;
    __syncthreads();
    part[tid] += v;
    __syncthreads();
  }
  int run = (tid == 0) ? 0 : part[tid - 1];
  for (int i = 0; i < per; ++i) {
    int idx = base + i;
    if (idx < n) {
      off[idx] = run;
      cur[idx] = run;
      run += cnt[idx];
    }
  }
  if (tid == 1023) off[n] = part[1023];
}

__global__ void k_fill2(const int* __restrict__ s1, const int* __restrict__ d1, int E1,
                        int* __restrict__ u1, int* __restrict__ l1,
                        const int* __restrict__ s2, const int* __restrict__ d2, int E2,
                        int* __restrict__ u2, int* __restrict__ l2) {
  int e = blockIdx.x * blockDim.x + threadIdx.x;
  if (e < E1) {
    int p = atomicAdd(&u1[d1[e]], 1);
    l1[p] = s1[e];
  } else if (e < E1 + E2) {
    int k = e - E1;
    int p = atomicAdd(&u2[d2[k]], 1);
    l2[p] = s2[k];
  }
}

// ---------------- mean aggregation (bf16 in/out, fp32 accum) ----------------

template <int VECB>
__global__ __launch_bounds__(64) void k_gather_bf(
    const unsigned short* __restrict__ X, int F,
    const int* __restrict__ off, const int* __restrict__ sl,
    unsigned short* __restrict__ out, const float* __restrict__ stats) {
  const int d = blockIdx.x;
  const int lane = threadIdx.x;
  const int b = off[d], e = off[d + 1];
  float acc[VECB];
#pragma unroll
  for (int i = 0; i < VECB; ++i) acc[i] = 0.f;
  const unsigned short* Xl = X + lane * VECB;
  for (int j = b; j < e; ++j) {
    const unsigned short* row = Xl + (size_t)sl[j] * F;
    if constexpr (VECB == 2) {
      unsigned v = *(const unsigned*)row;
      acc[0] += bf2f((unsigned short)(v & 0xffff));
      acc[1] += bf2f((unsigned short)(v >> 16));
    } else {
      uint2 v = *(const uint2*)row;
      acc[0] += bf2f((unsigned short)(v.x & 0xffff));
      acc[1] += bf2f((unsigned short)(v.x >> 16));
      acc[2] += bf2f((unsigned short)(v.y & 0xffff));
      acc[3] += bf2f((unsigned short)(v.y >> 16));
    }
  }
  float scale = 1.f / fmaxf((float)(e - b), 1.f);
  float mu = 0.f, inv = 1.f;
  if (stats) { mu = stats[2]; inv = stats[3]; }
  unsigned short* orow = out + (size_t)d * F + lane * VECB;
  if constexpr (VECB == 2) {
    unsigned v = ((unsigned)f2bf((acc[1] * scale - mu) * inv) << 16) |
                 (unsigned)f2bf((acc[0] * scale - mu) * inv);
    *(unsigned*)orow = v;
  } else {
    uint2 v;
    v.x = ((unsigned)f2bf((acc[1] * scale - mu) * inv) << 16) |
          (unsigned)f2bf((acc[0] * scale - mu) * inv);
    v.y = ((unsigned)f2bf((acc[3] * scale - mu) * inv) << 16) |
          (unsigned)f2bf((acc[2] * scale - mu) * inv);
    *(uint2*)orow = v;
  }
}

// ---------------- GEMM1: C = relu(A0@B0^T + A1@B1^T + b), bf16 out ----------------
// M x 256, K=128. Block: 4 waves x 16 rows; BN=32 (grid.x=8). B held in registers.

__global__ __launch_bounds__(256) void k_gemm1(
    const unsigned short* __restrict__ A0, const unsigned short* __restrict__ A1,
    const unsigned short* __restrict__ B0, const unsigned short* __restrict__ B1,
    const float* __restrict__ bias, unsigned short* __restrict__ C, int M) {
  constexpr int K = 128, N = 256;
  const int lane = threadIdx.x & 63;
  const int wv = threadIdx.x >> 6;
  const int r16 = lane & 15, hi = lane >> 4;
  const int n0 = blockIdx.x * 32;
  const int m0 = blockIdx.y * 64 + wv * 16;
  int arow = m0 + r16;
  if (arow >= M) arow = M - 1;
  const int koff = hi * 8;

  short8v bf[2][4][2];
#pragma unroll
  for (int s = 0; s < 2; ++s) {
    const unsigned short* B = s ? B1 : B0;
#pragma unroll
    for (int j = 0; j < 2; ++j) {
      const unsigned short* bp = B + (size_t)(n0 + j * 16 + r16) * K + koff;
#pragma unroll
      for (int t = 0; t < 4; ++t) bf[s][t][j] = *(const short8v*)(bp + t * 32);
    }
  }

  f32x4 acc[2];
  acc[0] = f32x4{0.f, 0.f, 0.f, 0.f};
  acc[1] = f32x4{0.f, 0.f, 0.f, 0.f};
#pragma unroll
  for (int s = 0; s < 2; ++s) {
    const unsigned short* ap = (s ? A1 : A0) + (size_t)arow * K + koff;
#pragma unroll
    for (int t = 0; t < 4; ++t) {
      short8v a = *(const short8v*)(ap + t * 32);
      acc[0] = __builtin_amdgcn_mfma_f32_16x16x32_bf16(a, bf[s][t][0], acc[0], 0, 0, 0);
      acc[1] = __builtin_amdgcn_mfma_f32_16x16x32_bf16(a, bf[s][t][1], acc[1], 0, 0, 0);
    }
  }

#pragma unroll
  for (int j = 0; j < 2; ++j) {
    const int col = n0 + j * 16 + r16;
    const float bj = bias[col];
#pragma unroll
    for (int r = 0; r < 4; ++r) {
      const int m = m0 + hi * 4 + r;
      if (m < M) C[(size_t)m * N + col] = f2bf(fmaxf(acc[j][r] + bj, 0.f));
    }
  }
}

// ---------------- GEMM2: C = A0@B0^T + A1@B1^T + b, fp32 out ----------------
// M x 64, K=256. Block: 4 waves x 16 rows; BN=16 (grid.x=4). B in registers.

__global__ __launch_bounds__(256) void k_gemm2(
    const unsigned short* __restrict__ A0, const unsigned short* __restrict__ A1,
    const unsigned short* __restrict__ B0, const unsigned short* __restrict__ B1,
    const float* __restrict__ bias, float* __restrict__ C, int M) {
  constexpr int K = 256, N = 64;
  const int lane = threadIdx.x & 63;
  const int wv = threadIdx.x >> 6;
  const int r16 = lane & 15, hi = lane >> 4;
  const int n0 = blockIdx.x * 16;
  const int m0 = blockIdx.y * 64 + wv * 16;
  int arow = m0 + r16;
  if (arow >= M) arow = M - 1;
  const int koff = hi * 8;

  short8v bf[2][8];
#pragma unroll
  for (int s = 0; s < 2; ++s) {
    const unsigned short* bp = (s ? B1 : B0) + (size_t)(n0 + r16) * K + koff;
#pragma unroll
    for (int t = 0; t < 8; ++t) bf[s][t] = *(const short8v*)(bp + t * 32);
  }

  f32x4 acc = f32x4{0.f, 0.f, 0.f, 0.f};
#pragma unroll
  for (int s = 0; s < 2; ++s) {
    const unsigned short* ap = (s ? A1 : A0) + (size_t)arow * K + koff;
#pragma unroll
    for (int t = 0; t < 8; ++t) {
      short8v a = *(const short8v*)(ap + t * 32);
      acc = __builtin_amdgcn_mfma_f32_16x16x32_bf16(a, bf[s][t], acc, 0, 0, 0);
    }
  }

  const int col = n0 + r16;
  const float bj = bias[col];
#pragma unroll
  for (int r = 0; r < 4; ++r) {
    const int m = m0 + hi * 4 + r;
    if (m < M) C[(size_t)m * N + col] = acc[r] + bj;
  }
}

// ---------------- LN stats: two-stage reduction over bf16 h ----------------

__global__ __launch_bounds__(256) void k_stats(const unsigned short* __restrict__ h, int n8,
                                               float* __restrict__ p1, float* __restrict__ p2) {
  float s1 = 0.f, s2 = 0.f;
  for (int i = blockIdx.x * 256 + threadIdx.x; i < n8; i += gridDim.x * 256) {
    uint4 v = ((const uint4*)h)[i];
    unsigned wds[4] = {v.x, v.y, v.z, v.w};
#pragma unroll
    for (int k = 0; k < 4; ++k) {
      float a = bf2f((unsigned short)(wds[k] & 0xffff));
      float b = bf2f((unsigned short)(wds[k] >> 16));
      s1 += a + b;
      s2 += a * a + b * b;
    }
  }
#pragma unroll
  for (int o = 32; o > 0; o >>= 1) {
    s1 += __shfl_down(s1, o);
    s2 += __shfl_down(s2, o);
  }
  __shared__ float l1[4], l2[4];
  const int tid = threadIdx.x;
  if ((tid & 63) == 0) { l1[tid >> 6] = s1; l2[tid >> 6] = s2; }
  __syncthreads();
  if (tid == 0) {
    p1[blockIdx.x] = l1[0] + l1[1] + l1[2] + l1[3];
    p2[blockIdx.x] = l2[0] + l2[1] + l2[2] + l2[3];
  }
}

__global__ __launch_bounds__(256) void k_finalize(const float* __restrict__ p1,
                                                  const float* __restrict__ p2,
                                                  float* __restrict__ stats, float invN) {
  const int tid = threadIdx.x;
  float s1 = p1[tid], s2 = p2[tid];
#pragma unroll
  for (int o = 32; o > 0; o >>= 1) {
    s1 += __shfl_down(s1, o);
    s2 += __shfl_down(s2, o);
  }
  __shared__ float l1[4], l2[4];
  if ((tid & 63) == 0) { l1[tid >> 6] = s1; l2[tid >> 6] = s2; }
  __syncthreads();
  if (tid == 0) {
    float t1 = l1[0] + l1[1] + l1[2] + l1[3];
    float t2 = l2[0] + l2[1] + l2[2] + l2[3];
    float mu = t1 * invN;
    float var = t2 * invN - mu * mu;
    stats[2] = mu;
    stats[3] = 1.f / sqrtf(var + LN_EPS);
  }
}

// ---------------- launch ----------------

extern "C" void kernel_launch(void* const* d_in, const int* in_sizes, int n_in,
                              void* d_out, int out_size, void* d_ws, size_t ws_size,
                              hipStream_t stream) {
  const float* x   = (const float*)d_in[0];
  const float* Ws1 = (const float*)d_in[1];
  const float* Wn1 = (const float*)d_in[2];
  const float* b1  = (const float*)d_in[3];
  const float* Ws2 = (const float*)d_in[4];
  const float* Wn2 = (const float*)d_in[5];
  const float* b2  = (const float*)d_in[6];
  const int* src1  = (const int*)d_in[7];
  const int* dst1  = (const int*)d_in[8];
  const int* src2  = (const int*)d_in[9];
  const int* dst2  = (const int*)d_in[10];

  const int E1 = in_sizes[7];
  const int E2 = in_sizes[9];
  const int N0 = 100000, N1 = 20000, N2 = 4000;
  const int FIN = 128, FH = 256, FOUT = 64;

  char* w = (char*)d_ws;
  auto alloc = [&](size_t bytes) {
    char* p = w;
    w += (bytes + 255) & ~(size_t)255;
    return p;
  };
  int* cnt1 = (int*)alloc((size_t)N1 * 4);
  int* cnt2 = (int*)alloc((size_t)N2 * 4);   // adjacent to cnt1: one memset covers both
  int* off1 = (int*)alloc((size_t)(N1 + 1) * 4);
  int* cur1 = (int*)alloc((size_t)N1 * 4);
  int* sl1  = (int*)alloc((size_t)E1 * 4);
  int* off2 = (int*)alloc((size_t)(N2 + 1) * 4);
  int* cur2 = (int*)alloc((size_t)N2 * 4);
  int* sl2  = (int*)alloc((size_t)E2 * 4);
  unsigned short* xbf   = (unsigned short*)alloc((size_t)N0 * FIN * 2);
  unsigned short* agg1b = (unsigned short*)alloc((size_t)N1 * FIN * 2);
  unsigned short* hbf   = (unsigned short*)alloc((size_t)N1 * FH * 2);
  unsigned short* a02b  = (unsigned short*)alloc((size_t)N2 * FH * 2);
  unsigned short* agg2b = (unsigned short*)alloc((size_t)N2 * FH * 2);
  unsigned short* w1sb  = (unsigned short*)alloc((size_t)FH * FIN * 2);
  unsigned short* w1nb  = (unsigned short*)alloc((size_t)FH * FIN * 2);
  unsigned short* w2sb  = (unsigned short*)alloc((size_t)FOUT * FH * 2);
  unsigned short* w2nb  = (unsigned short*)alloc((size_t)FOUT * FH * 2);
  float* part1 = (float*)alloc(256 * 4);
  float* part2 = (float*)alloc(256 * 4);
  float* stats = (float*)alloc(64);

  // one memset covers cnt1+cnt2 (adjacent, 256B-aligned allocs)
  hipMemsetAsync(cnt1, 0, ((size_t)N1 * 4 + 255 & ~(size_t)255) + (size_t)N2 * 4, stream);

  // conversions (x + all weights, one launch)
  {
    int n4x = N0 * FIN / 4;
    int total = n4x + 2 * FH * FIN + 2 * FOUT * FH;
    k_cvt_all<<<(total + 255) / 256, 256, 0, stream>>>(
        x, xbf, n4x, Ws1, w1sb, FH * FIN, Wn1, w1nb, FH * FIN,
        Ws2, w2sb, FOUT * FH, Wn2, w2nb, FOUT * FH);
  }

  // CSR builds (fused)
  int Et = E1 + E2;
  k_count2<<<(Et + 255) / 256, 256, 0, stream>>>(dst1, E1, cnt1, dst2, E2, cnt2);
  k_scan2<<<2, 1024, 0, stream>>>(cnt1, N1, off1, cur1, cnt2, N2, off2, cur2);
  k_fill2<<<(Et + 255) / 256, 256, 0, stream>>>(src1, dst1, E1, cur1, sl1,
                                                src2, dst2, E2, cur2, sl2);

  // ---- layer 1 ----
  k_gather_bf<2><<<N1, 64, 0, stream>>>(xbf, FIN, off1, sl1, agg1b, nullptr);

  dim3 g1(FH / 32, (N1 + 63) / 64);
  k_gemm1<<<g1, 256, 0, stream>>>(xbf, agg1b, w1sb, w1nb, b1, hbf, N1);

  k_stats<<<256, 256, 0, stream>>>(hbf, N1 * FH / 8, part1, part2);
  k_finalize<<<1, 256, 0, stream>>>(part1, part2, stats, 1.f / ((float)N1 * (float)FH));

  // ---- layer 2 ----
  {
    int n4 = N2 * FH / 4;
    k_affine<<<(n4 + 255) / 256, 256, 0, stream>>>(hbf, a02b, n4, stats);
  }
  k_gather_bf<4><<<N2, 64, 0, stream>>>(hbf, FH, off2, sl2, agg2b, stats);

  dim3 g2(FOUT / 16, (N2 + 63) / 64);
  k_gemm2<<<g2, 256, 0, stream>>>(a02b, agg2b, w2sb, w2nb, b2, (float*)d_out, N2);
}

// Round 4
// 169.320 us; speedup vs baseline: 2.0302x; 1.1759x over previous
//
#include <hip/hip_runtime.h>

#define LN_EPS 1e-5f

typedef __attribute__((ext_vector_type(8))) short short8v;
typedef __attribute__((ext_vector_type(4))) float f32x4;

__device__ __forceinline__ unsigned short f2bf(float f) {
  union { float f; unsigned u; } v; v.f = f;
  unsigned r = v.u + 0x7FFFu + ((v.u >> 16) & 1u);
  return (unsigned short)(r >> 16);
}
__device__ __forceinline__ float bf2f(unsigned short b) {
  union { unsigned u; float f; } v; v.u = ((unsigned)b) << 16;
  return v.f;
}
__device__ __forceinline__ float lo16(unsigned v) { return bf2f((unsigned short)(v & 0xffff)); }
__device__ __forceinline__ float hi16(unsigned v) { return bf2f((unsigned short)(v >> 16)); }

// ---------------- prep: zero cnt arrays + convert x and all weights to bf16 ----------------

__global__ __launch_bounds__(256) void k_prep(
    int* __restrict__ cntz, int nz4,
    const float* __restrict__ x, unsigned short* __restrict__ xbf, int n4x,
    const float* __restrict__ wa, unsigned short* __restrict__ oa, int na4,
    const float* __restrict__ wb, unsigned short* __restrict__ ob, int nb4,
    const float* __restrict__ wc, unsigned short* __restrict__ oc, int nc4,
    const float* __restrict__ wd, unsigned short* __restrict__ od, int nd4) {
  int i = blockIdx.x * 256 + threadIdx.x;
  if (i < nz4) { ((int4*)cntz)[i] = make_int4(0, 0, 0, 0); return; }
  i -= nz4;
  const float* src;
  unsigned short* dst;
  if (i < n4x) { src = x; dst = xbf; }
  else {
    i -= n4x;
    if (i < na4) { src = wa; dst = oa; }
    else { i -= na4;
      if (i < nb4) { src = wb; dst = ob; }
      else { i -= nb4;
        if (i < nc4) { src = wc; dst = oc; }
        else { i -= nc4;
          if (i < nd4) { src = wd; dst = od; }
          else return;
        }
      }
    }
  }
  float4 v = ((const float4*)src)[i];
  ushort4 o;
  o.x = f2bf(v.x); o.y = f2bf(v.y); o.z = f2bf(v.z); o.w = f2bf(v.w);
  ((ushort4*)dst)[i] = o;
}

// ---------------- CSR build (both graphs fused) ----------------

__global__ void k_count2(const int* __restrict__ d1, int E1, int* __restrict__ c1,
                         const int* __restrict__ d2, int E2, int* __restrict__ c2) {
  int e = blockIdx.x * blockDim.x + threadIdx.x;
  if (e < E1) atomicAdd(&c1[d1[e]], 1);
  else if (e < E1 + E2) atomicAdd(&c2[d2[e - E1]], 1);
}

__global__ __launch_bounds__(1024) void k_scan2(
    const int* __restrict__ c1, int n1, int* __restrict__ o1, int* __restrict__ u1,
    const int* __restrict__ c2, int n2, int* __restrict__ o2, int* __restrict__ u2) {
  const int* cnt = blockIdx.x ? c2 : c1;
  int n = blockIdx.x ? n2 : n1;
  int* off = blockIdx.x ? o2 : o1;
  int* cur = blockIdx.x ? u2 : u1;
  __shared__ int part[1024];
  const int tid = threadIdx.x;
  const int per = (n + 1023) >> 10;
  const int base = tid * per;
  int s = 0;
  for (int i = 0; i < per; ++i) {
    int idx = base + i;
    if (idx < n) s += cnt[idx];
  }
  part[tid] = s;
  __syncthreads();
  for (int d = 1; d < 1024; d <<= 1) {
    int v = (tid >= d) ? part[tid - d] : 0;
    __syncthreads();
    part[tid] += v;
    __syncthreads();
  }
  int run = (tid == 0) ? 0 : part[tid - 1];
  for (int i = 0; i < per; ++i) {
    int idx = base + i;
    if (idx < n) {
      off[idx] = run;
      cur[idx] = run;
      run += cnt[idx];
    }
  }
  if (tid == 1023) off[n] = part[1023];
}

__global__ void k_fill2(const int* __restrict__ s1, const int* __restrict__ d1, int E1,
                        int* __restrict__ u1, int* __restrict__ l1,
                        const int* __restrict__ s2, const int* __restrict__ d2, int E2,
                        int* __restrict__ u2, int* __restrict__ l2) {
  int e = blockIdx.x * blockDim.x + threadIdx.x;
  if (e < E1) {
    int p = atomicAdd(&u1[d1[e]], 1);
    l1[p] = s1[e];
  } else if (e < E1 + E2) {
    int k = e - E1;
    int p = atomicAdd(&u2[d2[k]], 1);
    l2[p] = s2[k];
  }
}

// ---------------- mean aggregation: wave per node, shfl-broadcast indices ----------------
// raw mean (no affine); VECB bf16 elems per lane

template <int VECB>
__global__ __launch_bounds__(64) void k_gather_bf(
    const unsigned short* __restrict__ X, int F,
    const int* __restrict__ off, const int* __restrict__ sl,
    unsigned short* __restrict__ out) {
  const int d = blockIdx.x;
  const int lane = threadIdx.x;
  const int b = off[d], e = off[d + 1];
  float acc[VECB];
#pragma unroll
  for (int i = 0; i < VECB; ++i) acc[i] = 0.f;
  const unsigned short* Xl = X + lane * VECB;

  for (int j = b; j < e; j += 64) {
    int idx = (j + lane < e) ? sl[j + lane] : 0;
    const int n = min(64, e - j);
    int t = 0;
    for (; t + 4 <= n; t += 4) {
      int s0 = __shfl(idx, t), s1 = __shfl(idx, t + 1);
      int s2 = __shfl(idx, t + 2), s3 = __shfl(idx, t + 3);
      if constexpr (VECB == 2) {
        unsigned v0 = *(const unsigned*)(Xl + (size_t)s0 * F);
        unsigned v1 = *(const unsigned*)(Xl + (size_t)s1 * F);
        unsigned v2 = *(const unsigned*)(Xl + (size_t)s2 * F);
        unsigned v3 = *(const unsigned*)(Xl + (size_t)s3 * F);
        acc[0] += lo16(v0) + lo16(v1) + lo16(v2) + lo16(v3);
        acc[1] += hi16(v0) + hi16(v1) + hi16(v2) + hi16(v3);
      } else {
        uint2 v0 = *(const uint2*)(Xl + (size_t)s0 * F);
        uint2 v1 = *(const uint2*)(Xl + (size_t)s1 * F);
        uint2 v2 = *(const uint2*)(Xl + (size_t)s2 * F);
        uint2 v3 = *(const uint2*)(Xl + (size_t)s3 * F);
        acc[0] += lo16(v0.x) + lo16(v1.x) + lo16(v2.x) + lo16(v3.x);
        acc[1] += hi16(v0.x) + hi16(v1.x) + hi16(v2.x) + hi16(v3.x);
        acc[2] += lo16(v0.y) + lo16(v1.y) + lo16(v2.y) + lo16(v3.y);
        acc[3] += hi16(v0.y) + hi16(v1.y) + hi16(v2.y) + hi16(v3.y);
      }
    }
    for (; t < n; ++t) {
      int s = __shfl(idx, t);
      if constexpr (VECB == 2) {
        unsigned v = *(const unsigned*)(Xl + (size_t)s * F);
        acc[0] += lo16(v);
        acc[1] += hi16(v);
      } else {
        uint2 v = *(const uint2*)(Xl + (size_t)s * F);
        acc[0] += lo16(v.x);
        acc[1] += hi16(v.x);
        acc[2] += lo16(v.y);
        acc[3] += hi16(v.y);
      }
    }
  }

  float scale = 1.f / fmaxf((float)(e - b), 1.f);
  unsigned short* orow = out + (size_t)d * F + lane * VECB;
  if constexpr (VECB == 2) {
    unsigned v = ((unsigned)f2bf(acc[1] * scale) << 16) | (unsigned)f2bf(acc[0] * scale);
    *(unsigned*)orow = v;
  } else {
    uint2 v;
    v.x = ((unsigned)f2bf(acc[1] * scale) << 16) | (unsigned)f2bf(acc[0] * scale);
    v.y = ((unsigned)f2bf(acc[3] * scale) << 16) | (unsigned)f2bf(acc[2] * scale);
    *(uint2*)orow = v;
  }
}

// ---------------- GEMM1: h = relu(A0@B0^T + A1@B1^T + b), bf16 out + stat partials ----------------
// M x 256, K=128. 4 waves x 16 rows; BN=32. B in registers.

__global__ __launch_bounds__(256) void k_gemm1(
    const unsigned short* __restrict__ A0, const unsigned short* __restrict__ A1,
    const unsigned short* __restrict__ B0, const unsigned short* __restrict__ B1,
    const float* __restrict__ bias, unsigned short* __restrict__ C, int M,
    float* __restrict__ part1, float* __restrict__ part2) {
  constexpr int K = 128, N = 256;
  const int lane = threadIdx.x & 63;
  const int wv = threadIdx.x >> 6;
  const int r16 = lane & 15, hi = lane >> 4;
  const int n0 = blockIdx.x * 32;
  const int m0 = blockIdx.y * 64 + wv * 16;
  int arow = m0 + r16;
  if (arow >= M) arow = M - 1;
  const int koff = hi * 8;

  short8v bf[2][4][2];
#pragma unroll
  for (int s = 0; s < 2; ++s) {
    const unsigned short* B = s ? B1 : B0;
#pragma unroll
    for (int j = 0; j < 2; ++j) {
      const unsigned short* bp = B + (size_t)(n0 + j * 16 + r16) * K + koff;
#pragma unroll
      for (int t = 0; t < 4; ++t) bf[s][t][j] = *(const short8v*)(bp + t * 32);
    }
  }

  f32x4 acc[2];
  acc[0] = f32x4{0.f, 0.f, 0.f, 0.f};
  acc[1] = f32x4{0.f, 0.f, 0.f, 0.f};
#pragma unroll
  for (int s = 0; s < 2; ++s) {
    const unsigned short* ap = (s ? A1 : A0) + (size_t)arow * K + koff;
#pragma unroll
    for (int t = 0; t < 4; ++t) {
      short8v a = *(const short8v*)(ap + t * 32);
      acc[0] = __builtin_amdgcn_mfma_f32_16x16x32_bf16(a, bf[s][t][0], acc[0], 0, 0, 0);
      acc[1] = __builtin_amdgcn_mfma_f32_16x16x32_bf16(a, bf[s][t][1], acc[1], 0, 0, 0);
    }
  }

  float s1 = 0.f, s2 = 0.f;
#pragma unroll
  for (int j = 0; j < 2; ++j) {
    const int col = n0 + j * 16 + r16;
    const float bj = bias[col];
#pragma unroll
    for (int r = 0; r < 4; ++r) {
      const int m = m0 + hi * 4 + r;
      if (m < M) {
        float c = fmaxf(acc[j][r] + bj, 0.f);
        s1 += c;
        s2 += c * c;
        C[(size_t)m * N + col] = f2bf(c);
      }
    }
  }

#pragma unroll
  for (int o = 32; o > 0; o >>= 1) {
    s1 += __shfl_down(s1, o);
    s2 += __shfl_down(s2, o);
  }
  __shared__ float l1[4], l2[4];
  if (lane == 0) { l1[wv] = s1; l2[wv] = s2; }
  __syncthreads();
  if (threadIdx.x == 0) {
    const int bid = blockIdx.y * gridDim.x + blockIdx.x;
    part1[bid] = l1[0] + l1[1] + l1[2] + l1[3];
    part2[bid] = l2[0] + l2[1] + l2[2] + l2[3];
  }
}

__global__ __launch_bounds__(256) void k_finalize(const float* __restrict__ p1,
                                                  const float* __restrict__ p2,
                                                  int nPart, float* __restrict__ stats,
                                                  float invN) {
  const int tid = threadIdx.x;
  float s1 = 0.f, s2 = 0.f;
  for (int i = tid; i < nPart; i += 256) { s1 += p1[i]; s2 += p2[i]; }
#pragma unroll
  for (int o = 32; o > 0; o >>= 1) {
    s1 += __shfl_down(s1, o);
    s2 += __shfl_down(s2, o);
  }
  __shared__ float l1[4], l2[4];
  if ((tid & 63) == 0) { l1[tid >> 6] = s1; l2[tid >> 6] = s2; }
  __syncthreads();
  if (tid == 0) {
    float t1 = l1[0] + l1[1] + l1[2] + l1[3];
    float t2 = l2[0] + l2[1] + l2[2] + l2[3];
    float mu = t1 * invN;
    float var = t2 * invN - mu * mu;
    stats[2] = mu;
    stats[3] = 1.f / sqrtf(var + LN_EPS);
  }
}

// ---------------- GEMM2: C = aff(A0)@B0^T + aff(A1)@B1^T + b, fp32 out ----------------
// M x 64, K=256. 4 waves x 16 rows; BN=16. B in registers; LN affine folded into A loads.

__device__ __forceinline__ short8v affine8(short8v v, float mu, float inv) {
  short8v r;
#pragma unroll
  for (int i = 0; i < 8; ++i) {
    r[i] = (short)f2bf((bf2f((unsigned short)v[i]) - mu) * inv);
  }
  return r;
}

__global__ __launch_bounds__(256) void k_gemm2(
    const unsigned short* __restrict__ A0, const unsigned short* __restrict__ A1,
    const unsigned short* __restrict__ B0, const unsigned short* __restrict__ B1,
    const float* __restrict__ bias, float* __restrict__ C, int M,
    const float* __restrict__ stats) {
  constexpr int K = 256, N = 64;
  const int lane = threadIdx.x & 63;
  const int wv = threadIdx.x >> 6;
  const int r16 = lane & 15, hi = lane >> 4;
  const int n0 = blockIdx.x * 16;
  const int m0 = blockIdx.y * 64 + wv * 16;
  int arow = m0 + r16;
  if (arow >= M) arow = M - 1;
  const int koff = hi * 8;
  const float mu = stats[2], inv = stats[3];

  short8v bfr[2][8];
#pragma unroll
  for (int s = 0; s < 2; ++s) {
    const unsigned short* bp = (s ? B1 : B0) + (size_t)(n0 + r16) * K + koff;
#pragma unroll
    for (int t = 0; t < 8; ++t) bfr[s][t] = *(const short8v*)(bp + t * 32);
  }

  f32x4 acc = f32x4{0.f, 0.f, 0.f, 0.f};
#pragma unroll
  for (int s = 0; s < 2; ++s) {
    const unsigned short* ap = (s ? A1 : A0) + (size_t)arow * K + koff;
#pragma unroll
    for (int t = 0; t < 8; ++t) {
      short8v a = affine8(*(const short8v*)(ap + t * 32), mu, inv);
      acc = __builtin_amdgcn_mfma_f32_16x16x32_bf16(a, bfr[s][t], acc, 0, 0, 0);
    }
  }

  const int col = n0 + r16;
  const float bj = bias[col];
#pragma unroll
  for (int r = 0; r < 4; ++r) {
    const int m = m0 + hi * 4 + r;
    if (m < M) C[(size_t)m * N + col] = acc[r] + bj;
  }
}

// ---------------- launch ----------------

extern "C" void kernel_launch(void* const* d_in, const int* in_sizes, int n_in,
                              void* d_out, int out_size, void* d_ws, size_t ws_size,
                              hipStream_t stream) {
  const float* x   = (const float*)d_in[0];
  const float* Ws1 = (const float*)d_in[1];
  const float* Wn1 = (const float*)d_in[2];
  const float* b1  = (const float*)d_in[3];
  const float* Ws2 = (const float*)d_in[4];
  const float* Wn2 = (const float*)d_in[5];
  const float* b2  = (const float*)d_in[6];
  const int* src1  = (const int*)d_in[7];
  const int* dst1  = (const int*)d_in[8];
  const int* src2  = (const int*)d_in[9];
  const int* dst2  = (const int*)d_in[10];

  const int E1 = in_sizes[7];
  const int E2 = in_sizes[9];
  const int N0 = 100000, N1 = 20000, N2 = 4000;
  const int FIN = 128, FH = 256, FOUT = 64;

  char* w = (char*)d_ws;
  auto alloc = [&](size_t bytes) {
    char* p = w;
    w += (bytes + 255) & ~(size_t)255;
    return p;
  };
  int* cnt1 = (int*)alloc((size_t)(N1 + N2) * 4);  // cnt2 = cnt1 + N1, zeroed together
  int* cnt2 = cnt1 + N1;
  int* off1 = (int*)alloc((size_t)(N1 + 1) * 4);
  int* cur1 = (int*)alloc((size_t)N1 * 4);
  int* sl1  = (int*)alloc((size_t)E1 * 4);
  int* off2 = (int*)alloc((size_t)(N2 + 1) * 4);
  int* cur2 = (int*)alloc((size_t)N2 * 4);
  int* sl2  = (int*)alloc((size_t)E2 * 4);
  unsigned short* xbf   = (unsigned short*)alloc((size_t)N0 * FIN * 2);
  unsigned short* agg1b = (unsigned short*)alloc((size_t)N1 * FIN * 2);
  unsigned short* hbf   = (unsigned short*)alloc((size_t)N1 * FH * 2);
  unsigned short* agg2b = (unsigned short*)alloc((size_t)N2 * FH * 2);
  unsigned short* w1sb  = (unsigned short*)alloc((size_t)FH * FIN * 2);
  unsigned short* w1nb  = (unsigned short*)alloc((size_t)FH * FIN * 2);
  unsigned short* w2sb  = (unsigned short*)alloc((size_t)FOUT * FH * 2);
  unsigned short* w2nb  = (unsigned short*)alloc((size_t)FOUT * FH * 2);
  const int nPart = ((N1 + 63) / 64) * (FH / 32);
  float* part1 = (float*)alloc((size_t)nPart * 4);
  float* part2 = (float*)alloc((size_t)nPart * 4);
  float* stats = (float*)alloc(64);

  // prep: zero counters + all bf16 conversions, one launch
  {
    const int nz4 = (N1 + N2) / 4;
    const int n4x = N0 * FIN / 4;
    const int na4 = FH * FIN / 4, nc4 = FOUT * FH / 4;
    const int total = nz4 + n4x + 2 * na4 + 2 * nc4;
    k_prep<<<(total + 255) / 256, 256, 0, stream>>>(
        cnt1, nz4, x, xbf, n4x,
        Ws1, w1sb, na4, Wn1, w1nb, na4,
        Ws2, w2sb, nc4, Wn2, w2nb, nc4);
  }

  // CSR builds (fused)
  const int Et = E1 + E2;
  k_count2<<<(Et + 255) / 256, 256, 0, stream>>>(dst1, E1, cnt1, dst2, E2, cnt2);
  k_scan2<<<2, 1024, 0, stream>>>(cnt1, N1, off1, cur1, cnt2, N2, off2, cur2);
  k_fill2<<<(Et + 255) / 256, 256, 0, stream>>>(src1, dst1, E1, cur1, sl1,
                                                src2, dst2, E2, cur2, sl2);

  // ---- layer 1 ----
  k_gather_bf<2><<<N1, 64, 0, stream>>>(xbf, FIN, off1, sl1, agg1b);

  dim3 g1(FH / 32, (N1 + 63) / 64);
  k_gemm1<<<g1, 256, 0, stream>>>(xbf, agg1b, w1sb, w1nb, b1, hbf, N1, part1, part2);
  k_finalize<<<1, 256, 0, stream>>>(part1, part2, nPart, stats,
                                    1.f / ((float)N1 * (float)FH));

  // ---- layer 2 ----
  k_gather_bf<4><<<N2, 64, 0, stream>>>(hbf, FH, off2, sl2, agg2b);

  dim3 g2(FOUT / 16, (N2 + 63) / 64);
  k_gemm2<<<g2, 256, 0, stream>>>(hbf, agg2b, w2sb, w2nb, b2, (float*)d_out, N2, stats);
}

// Round 7
// 166.519 us; speedup vs baseline: 2.0643x; 1.0168x over previous
//
#include <hip/hip_runtime.h>

#define LN_EPS 1e-5f

typedef __attribute__((ext_vector_type(8))) short short8v;
typedef __attribute__((ext_vector_type(4))) float f32x4;

__device__ __forceinline__ unsigned short f2bf(float f) {
  union { float f; unsigned u; } v; v.f = f;
  unsigned r = v.u + 0x7FFFu + ((v.u >> 16) & 1u);
  return (unsigned short)(r >> 16);
}
__device__ __forceinline__ float bf2f(unsigned short b) {
  union { unsigned u; float f; } v; v.u = ((unsigned)b) << 16;
  return v.f;
}
__device__ __forceinline__ float lo16(unsigned v) { return bf2f((unsigned short)(v & 0xffff)); }
__device__ __forceinline__ float hi16(unsigned v) { return bf2f((unsigned short)(v >> 16)); }
__device__ __forceinline__ unsigned pack2(float lo, float hi) {
  return ((unsigned)f2bf(hi) << 16) | (unsigned)f2bf(lo);
}

// ---------------- prep: zero cnt arrays + convert x and weights to bf16 ----------------

__global__ __launch_bounds__(256) void k_prep(
    int* __restrict__ cntz, int nz4,
    const float* __restrict__ x, unsigned short* __restrict__ xbf, int n4x,
    const float* __restrict__ wa, unsigned short* __restrict__ oa, int na4,
    const float* __restrict__ wb, unsigned short* __restrict__ ob, int nb4,
    const float* __restrict__ wc, unsigned short* __restrict__ oc, int nc4,
    const float* __restrict__ wd, unsigned short* __restrict__ od, int nd4) {
  int i = blockIdx.x * 256 + threadIdx.x;
  if (i < nz4) { ((int4*)cntz)[i] = make_int4(0, 0, 0, 0); return; }
  i -= nz4;
  const float* src;
  unsigned short* dst;
  if (i < n4x) { src = x; dst = xbf; }
  else {
    i -= n4x;
    if (i < na4) { src = wa; dst = oa; }
    else { i -= na4;
      if (i < nb4) { src = wb; dst = ob; }
      else { i -= nb4;
        if (i < nc4) { src = wc; dst = oc; }
        else { i -= nc4;
          if (i < nd4) { src = wd; dst = od; }
          else return;
        }
      }
    }
  }
  float4 v = ((const float4*)src)[i];
  ushort4 o;
  o.x = f2bf(v.x); o.y = f2bf(v.y); o.z = f2bf(v.z); o.w = f2bf(v.w);
  ((ushort4*)dst)[i] = o;
}

// ---------------- CSR build (both graphs fused) ----------------

__global__ void k_count2(const int* __restrict__ d1, int E1, int* __restrict__ c1,
                         const int* __restrict__ d2, int E2, int* __restrict__ c2) {
  int e = blockIdx.x * blockDim.x + threadIdx.x;
  if (e < E1) atomicAdd(&c1[d1[e]], 1);
  else if (e < E1 + E2) atomicAdd(&c2[d2[e - E1]], 1);
}

__global__ __launch_bounds__(1024) void k_scan2(
    const int* __restrict__ c1, int n1, int* __restrict__ o1, int* __restrict__ u1,
    const int* __restrict__ c2, int n2, int* __restrict__ o2, int* __restrict__ u2) {
  const int* cnt = blockIdx.x ? c2 : c1;
  int n = blockIdx.x ? n2 : n1;
  int* off = blockIdx.x ? o2 : o1;
  int* cur = blockIdx.x ? u2 : u1;
  __shared__ int part[1024];
  const int tid = threadIdx.x;
  const int per = (n + 1023) >> 10;
  const int base = tid * per;
  int s = 0;
  for (int i = 0; i < per; ++i) {
    int idx = base + i;
    if (idx < n) s += cnt[idx];
  }
  part[tid] = s;
  __syncthreads();
  for (int d = 1; d < 1024; d <<= 1) {
    int v = (tid >= d) ? part[tid - d] : 0;
    __syncthreads();
    part[tid] += v;
    __syncthreads();
  }
  int run = (tid == 0) ? 0 : part[tid - 1];
  for (int i = 0; i < per; ++i) {
    int idx = base + i;
    if (idx < n) {
      off[idx] = run;
      cur[idx] = run;
      run += cnt[idx];
    }
  }
  if (tid == 1023) off[n] = part[1023];
}

__global__ void k_fill2(const int* __restrict__ s1, const int* __restrict__ d1, int E1,
                        int* __restrict__ u1, int* __restrict__ l1,
                        const int* __restrict__ s2, const int* __restrict__ d2, int E2,
                        int* __restrict__ u2, int* __restrict__ l2) {
  int e = blockIdx.x * blockDim.x + threadIdx.x;
  if (e < E1) {
    int p = atomicAdd(&u1[d1[e]], 1);
    l1[p] = s1[e];
  } else if (e < E1 + E2) {
    int k = e - E1;
    int p = atomicAdd(&u2[d2[k]], 1);
    l2[p] = s2[k];
  }
}

// ---------------- mean aggregation: R4-proven body (wave-uniform shfl broadcast),
// packed 4 nodes per 256-thread block ----------------

__device__ __forceinline__ void gather_node2(
    const unsigned short* __restrict__ X, int F, int lane, int b, int e,
    unsigned short* __restrict__ orow) {
  float acc0 = 0.f, acc1 = 0.f;
  const unsigned short* Xl = X + lane * 2;
  for (int j = b; j < e; j += 64) {
    int idx = (j + lane < e) ? __builtin_nontemporal_load(&((const int*)0)[0]) * 0 + ((const int*)X, 0) : 0;
    (void)idx;
    break;
  }
  (void)acc0; (void)acc1; (void)Xl; (void)orow;
}

template <int VECB>
__global__ __launch_bounds__(256) void k_gather4(
    const unsigned short* __restrict__ X, int F,
    const int* __restrict__ off, const int* __restrict__ sl,
    unsigned short* __restrict__ out, int nNodes) {
  const int d = blockIdx.x * 4 + (threadIdx.x >> 6);
  if (d >= nNodes) return;
  const int lane = threadIdx.x & 63;
  const int b = off[d], e = off[d + 1];
  float acc[VECB];
#pragma unroll
  for (int i = 0; i < VECB; ++i) acc[i] = 0.f;
  const unsigned short* Xl = X + lane * VECB;

  for (int j = b; j < e; j += 64) {
    int idx = (j + lane < e) ? sl[j + lane] : 0;
    const int n = min(64, e - j);
    int t = 0;
    for (; t + 4 <= n; t += 4) {
      int s0 = __shfl(idx, t), s1 = __shfl(idx, t + 1);
      int s2 = __shfl(idx, t + 2), s3 = __shfl(idx, t + 3);
      if constexpr (VECB == 2) {
        unsigned v0 = *(const unsigned*)(Xl + (size_t)s0 * F);
        unsigned v1 = *(const unsigned*)(Xl + (size_t)s1 * F);
        unsigned v2 = *(const unsigned*)(Xl + (size_t)s2 * F);
        unsigned v3 = *(const unsigned*)(Xl + (size_t)s3 * F);
        acc[0] += lo16(v0) + lo16(v1) + lo16(v2) + lo16(v3);
        acc[1] += hi16(v0) + hi16(v1) + hi16(v2) + hi16(v3);
      } else {
        uint2 v0 = *(const uint2*)(Xl + (size_t)s0 * F);
        uint2 v1 = *(const uint2*)(Xl + (size_t)s1 * F);
        uint2 v2 = *(const uint2*)(Xl + (size_t)s2 * F);
        uint2 v3 = *(const uint2*)(Xl + (size_t)s3 * F);
        acc[0] += lo16(v0.x) + lo16(v1.x) + lo16(v2.x) + lo16(v3.x);
        acc[1] += hi16(v0.x) + hi16(v1.x) + hi16(v2.x) + hi16(v3.x);
        acc[2] += lo16(v0.y) + lo16(v1.y) + lo16(v2.y) + lo16(v3.y);
        acc[3] += hi16(v0.y) + hi16(v1.y) + hi16(v2.y) + hi16(v3.y);
      }
    }
    for (; t < n; ++t) {
      int s = __shfl(idx, t);
      if constexpr (VECB == 2) {
        unsigned v = *(const unsigned*)(Xl + (size_t)s * F);
        acc[0] += lo16(v);
        acc[1] += hi16(v);
      } else {
        uint2 v = *(const uint2*)(Xl + (size_t)s * F);
        acc[0] += lo16(v.x);
        acc[1] += hi16(v.x);
        acc[2] += lo16(v.y);
        acc[3] += hi16(v.y);
      }
    }
  }

  const float sc = 1.f / fmaxf((float)(e - b), 1.f);
  unsigned short* orow = out + (size_t)d * F + lane * VECB;
  if constexpr (VECB == 2) {
    *(unsigned*)orow = pack2(acc[0] * sc, acc[1] * sc);
  } else {
    uint2 v;
    v.x = pack2(acc[0] * sc, acc[1] * sc);
    v.y = pack2(acc[2] * sc, acc[3] * sc);
    *(uint2*)orow = v;
  }
}

// ---------------- gather2 + LN finalize merged (independent works, one launch) ----------------
// Blocks [0, nGB): gather (VECB=4, F=256), 4 nodes each. Block nGB: finalize.

__global__ __launch_bounds__(256) void k_gather2_fin(
    const unsigned short* __restrict__ X,
    const int* __restrict__ off, const int* __restrict__ sl,
    unsigned short* __restrict__ out, int nNodes, int nGB,
    const float* __restrict__ p1, const float* __restrict__ p2, int nPart,
    float* __restrict__ stats, float invN) {
  if ((int)blockIdx.x == nGB) {
    const int tid = threadIdx.x;
    float s1 = 0.f, s2 = 0.f;
    for (int i = tid; i < nPart; i += 256) { s1 += p1[i]; s2 += p2[i]; }
#pragma unroll
    for (int o = 32; o > 0; o >>= 1) {
      s1 += __shfl_down(s1, o);
      s2 += __shfl_down(s2, o);
    }
    __shared__ float l1[4], l2[4];
    if ((tid & 63) == 0) { l1[tid >> 6] = s1; l2[tid >> 6] = s2; }
    __syncthreads();
    if (tid == 0) {
      float t1 = l1[0] + l1[1] + l1[2] + l1[3];
      float t2 = l2[0] + l2[1] + l2[2] + l2[3];
      float mu = t1 * invN;
      float var = t2 * invN - mu * mu;
      stats[2] = mu;
      stats[3] = 1.f / sqrtf(var + LN_EPS);
    }
    return;
  }

  constexpr int F = 256;
  const int d = blockIdx.x * 4 + (threadIdx.x >> 6);
  if (d >= nNodes) return;
  const int lane = threadIdx.x & 63;
  const int b = off[d], e = off[d + 1];
  float acc[4] = {0.f, 0.f, 0.f, 0.f};
  const unsigned short* Xl = X + lane * 4;

  for (int j = b; j < e; j += 64) {
    int idx = (j + lane < e) ? sl[j + lane] : 0;
    const int n = min(64, e - j);
    int t = 0;
    for (; t + 4 <= n; t += 4) {
      int s0 = __shfl(idx, t), s1 = __shfl(idx, t + 1);
      int s2 = __shfl(idx, t + 2), s3 = __shfl(idx, t + 3);
      uint2 v0 = *(const uint2*)(Xl + (size_t)s0 * F);
      uint2 v1 = *(const uint2*)(Xl + (size_t)s1 * F);
      uint2 v2 = *(const uint2*)(Xl + (size_t)s2 * F);
      uint2 v3 = *(const uint2*)(Xl + (size_t)s3 * F);
      acc[0] += lo16(v0.x) + lo16(v1.x) + lo16(v2.x) + lo16(v3.x);
      acc[1] += hi16(v0.x) + hi16(v1.x) + hi16(v2.x) + hi16(v3.x);
      acc[2] += lo16(v0.y) + lo16(v1.y) + lo16(v2.y) + lo16(v3.y);
      acc[3] += hi16(v0.y) + hi16(v1.y) + hi16(v2.y) + hi16(v3.y);
    }
    for (; t < n; ++t) {
      int s = __shfl(idx, t);
      uint2 v = *(const uint2*)(Xl + (size_t)s * F);
      acc[0] += lo16(v.x);
      acc[1] += hi16(v.x);
      acc[2] += lo16(v.y);
      acc[3] += hi16(v.y);
    }
  }

  const float sc = 1.f / fmaxf((float)(e - b), 1.f);
  uint2 v;
  v.x = pack2(acc[0] * sc, acc[1] * sc);
  v.y = pack2(acc[2] * sc, acc[3] * sc);
  *(uint2*)(out + (size_t)d * F + lane * 4) = v;
}

// ---------------- GEMM1: h = relu(A0@B0^T + A1@B1^T + b), bf16 out + stat partials ----------------
// M x 256, K=128. 4 waves x 16 rows; BN=32. B in registers.

__global__ __launch_bounds__(256) void k_gemm1(
    const unsigned short* __restrict__ A0, const unsigned short* __restrict__ A1,
    const unsigned short* __restrict__ B0, const unsigned short* __restrict__ B1,
    const float* __restrict__ bias, unsigned short* __restrict__ C, int M,
    float* __restrict__ part1, float* __restrict__ part2) {
  constexpr int K = 128, N = 256;
  const int lane = threadIdx.x & 63;
  const int wv = threadIdx.x >> 6;
  const int r16 = lane & 15, hi = lane >> 4;
  const int n0 = blockIdx.x * 32;
  const int m0 = blockIdx.y * 64 + wv * 16;
  int arow = m0 + r16;
  if (arow >= M) arow = M - 1;
  const int koff = hi * 8;

  short8v bf[2][4][2];
#pragma unroll
  for (int s = 0; s < 2; ++s) {
    const unsigned short* B = s ? B1 : B0;
#pragma unroll
    for (int j = 0; j < 2; ++j) {
      const unsigned short* bp = B + (size_t)(n0 + j * 16 + r16) * K + koff;
#pragma unroll
      for (int t = 0; t < 4; ++t) bf[s][t][j] = *(const short8v*)(bp + t * 32);
    }
  }

  f32x4 acc[2];
  acc[0] = f32x4{0.f, 0.f, 0.f, 0.f};
  acc[1] = f32x4{0.f, 0.f, 0.f, 0.f};
#pragma unroll
  for (int s = 0; s < 2; ++s) {
    const unsigned short* ap = (s ? A1 : A0) + (size_t)arow * K + koff;
#pragma unroll
    for (int t = 0; t < 4; ++t) {
      short8v a = *(const short8v*)(ap + t * 32);
      acc[0] = __builtin_amdgcn_mfma_f32_16x16x32_bf16(a, bf[s][t][0], acc[0], 0, 0, 0);
      acc[1] = __builtin_amdgcn_mfma_f32_16x16x32_bf16(a, bf[s][t][1], acc[1], 0, 0, 0);
    }
  }

  float s1 = 0.f, s2 = 0.f;
#pragma unroll
  for (int j = 0; j < 2; ++j) {
    const int col = n0 + j * 16 + r16;
    const float bj = bias[col];
#pragma unroll
    for (int r = 0; r < 4; ++r) {
      const int m = m0 + hi * 4 + r;
      if (m < M) {
        float c = fmaxf(acc[j][r] + bj, 0.f);
        s1 += c;
        s2 += c * c;
        C[(size_t)m * N + col] = f2bf(c);
      }
    }
  }

#pragma unroll
  for (int o = 32; o > 0; o >>= 1) {
    s1 += __shfl_down(s1, o);
    s2 += __shfl_down(s2, o);
  }
  __shared__ float l1[4], l2[4];
  if (lane == 0) { l1[wv] = s1; l2[wv] = s2; }
  __syncthreads();
  if (threadIdx.x == 0) {
    const int bid = blockIdx.y * gridDim.x + blockIdx.x;
    part1[bid] = l1[0] + l1[1] + l1[2] + l1[3];
    part2[bid] = l2[0] + l2[1] + l2[2] + l2[3];
  }
}

// ---------------- GEMM2: C = aff(A0)@B0^T + aff(A1)@B1^T + b, fp32 out ----------------

__device__ __forceinline__ short8v affine8(short8v v, float mu, float inv) {
  short8v r;
#pragma unroll
  for (int i = 0; i < 8; ++i) {
    r[i] = (short)f2bf((bf2f((unsigned short)v[i]) - mu) * inv);
  }
  return r;
}

__global__ __launch_bounds__(256) void k_gemm2(
    const unsigned short* __restrict__ A0, const unsigned short* __restrict__ A1,
    const unsigned short* __restrict__ B0, const unsigned short* __restrict__ B1,
    const float* __restrict__ bias, float* __restrict__ C, int M,
    const float* __restrict__ stats) {
  constexpr int K = 256, N = 64;
  const int lane = threadIdx.x & 63;
  const int wv = threadIdx.x >> 6;
  const int r16 = lane & 15, hi = lane >> 4;
  const int n0 = blockIdx.x * 16;
  const int m0 = blockIdx.y * 64 + wv * 16;
  int arow = m0 + r16;
  if (arow >= M) arow = M - 1;
  const int koff = hi * 8;
  const float mu = stats[2], inv = stats[3];

  short8v bfr[2][8];
#pragma unroll
  for (int s = 0; s < 2; ++s) {
    const unsigned short* bp = (s ? B1 : B0) + (size_t)(n0 + r16) * K + koff;
#pragma unroll
    for (int t = 0; t < 8; ++t) bfr[s][t] = *(const short8v*)(bp + t * 32);
  }

  f32x4 acc = f32x4{0.f, 0.f, 0.f, 0.f};
#pragma unroll
  for (int s = 0; s < 2; ++s) {
    const unsigned short* ap = (s ? A1 : A0) + (size_t)arow * K + koff;
#pragma unroll
    for (int t = 0; t < 8; ++t) {
      short8v a = affine8(*(const short8v*)(ap + t * 32), mu, inv);
      acc = __builtin_amdgcn_mfma_f32_16x16x32_bf16(a, bfr[s][t], acc, 0, 0, 0);
    }
  }

  const int col = n0 + r16;
  const float bj = bias[col];
#pragma unroll
  for (int r = 0; r < 4; ++r) {
    const int m = m0 + hi * 4 + r;
    if (m < M) C[(size_t)m * N + col] = acc[r] + bj;
  }
}

// ---------------- launch ----------------

extern "C" void kernel_launch(void* const* d_in, const int* in_sizes, int n_in,
                              void* d_out, int out_size, void* d_ws, size_t ws_size,
                              hipStream_t stream) {
  const float* x   = (const float*)d_in[0];
  const float* Ws1 = (const float*)d_in[1];
  const float* Wn1 = (const float*)d_in[2];
  const float* b1  = (const float*)d_in[3];
  const float* Ws2 = (const float*)d_in[4];
  const float* Wn2 = (const float*)d_in[5];
  const float* b2  = (const float*)d_in[6];
  const int* src1  = (const int*)d_in[7];
  const int* dst1  = (const int*)d_in[8];
  const int* src2  = (const int*)d_in[9];
  const int* dst2  = (const int*)d_in[10];

  const int E1 = in_sizes[7];
  const int E2 = in_sizes[9];
  const int N0 = 100000, N1 = 20000, N2 = 4000;
  const int FIN = 128, FH = 256, FOUT = 64;

  char* w = (char*)d_ws;
  auto alloc = [&](size_t bytes) {
    char* p = w;
    w += (bytes + 255) & ~(size_t)255;
    return p;
  };
  // zero region: cnt1 | cnt2 — one int4-zeroed block in k_prep
  int* cnt1 = (int*)alloc((size_t)(N1 + N2) * 4);
  int* cnt2 = cnt1 + N1;
  int* off1 = (int*)alloc((size_t)(N1 + 1) * 4);
  int* cur1 = (int*)alloc((size_t)N1 * 4);
  int* sl1  = (int*)alloc((size_t)E1 * 4);
  int* off2 = (int*)alloc((size_t)(N2 + 1) * 4);
  int* cur2 = (int*)alloc((size_t)N2 * 4);
  int* sl2  = (int*)alloc((size_t)E2 * 4);
  unsigned short* xbf   = (unsigned short*)alloc((size_t)N0 * FIN * 2);
  unsigned short* agg1b = (unsigned short*)alloc((size_t)N1 * FIN * 2);
  unsigned short* hbf   = (unsigned short*)alloc((size_t)N1 * FH * 2);
  unsigned short* agg2b = (unsigned short*)alloc((size_t)N2 * FH * 2);
  unsigned short* w1sb  = (unsigned short*)alloc((size_t)FH * FIN * 2);
  unsigned short* w1nb  = (unsigned short*)alloc((size_t)FH * FIN * 2);
  unsigned short* w2sb  = (unsigned short*)alloc((size_t)FOUT * FH * 2);
  unsigned short* w2nb  = (unsigned short*)alloc((size_t)FOUT * FH * 2);
  const int nBlk1 = ((N1 + 63) / 64) * (FH / 32);
  float* part1 = (float*)alloc((size_t)nBlk1 * 4);
  float* part2 = (float*)alloc((size_t)nBlk1 * 4);
  float* stats = (float*)alloc(64);

  // prep: zero counters + all bf16 conversions, one launch
  {
    const int nz4 = (N1 + N2) / 4;
    const int n4x = N0 * FIN / 4;
    const int na4 = FH * FIN / 4, nc4 = FOUT * FH / 4;
    const int total = nz4 + n4x + 2 * na4 + 2 * nc4;
    k_prep<<<(total + 255) / 256, 256, 0, stream>>>(
        cnt1, nz4, x, xbf, n4x,
        Ws1, w1sb, na4, Wn1, w1nb, na4,
        Ws2, w2sb, nc4, Wn2, w2nb, nc4);
  }

  // CSR builds (fused)
  const int Et = E1 + E2;
  k_count2<<<(Et + 255) / 256, 256, 0, stream>>>(dst1, E1, cnt1, dst2, E2, cnt2);
  k_scan2<<<2, 1024, 0, stream>>>(cnt1, N1, off1, cur1, cnt2, N2, off2, cur2);
  k_fill2<<<(Et + 255) / 256, 256, 0, stream>>>(src1, dst1, E1, cur1, sl1,
                                                src2, dst2, E2, cur2, sl2);

  // ---- layer 1 ----
  k_gather4<2><<<(N1 + 3) / 4, 256, 0, stream>>>(xbf, FIN, off1, sl1, agg1b, N1);

  dim3 g1(FH / 32, (N1 + 63) / 64);
  k_gemm1<<<g1, 256, 0, stream>>>(xbf, agg1b, w1sb, w1nb, b1, hbf, N1, part1, part2);

  // ---- layer 2: gather2 + LN finalize in one launch (independent blocks) ----
  const int nGB = (N2 + 3) / 4;
  k_gather2_fin<<<nGB + 1, 256, 0, stream>>>(hbf, off2, sl2, agg2b, N2, nGB,
                                             part1, part2, nBlk1, stats,
                                             1.f / ((float)N1 * (float)FH));

  dim3 g2(FOUT / 16, (N2 + 63) / 64);
  k_gemm2<<<g2, 256, 0, stream>>>(hbf, agg2b, w2sb, w2nb, b2, (float*)d_out, N2, stats);
}